// Round 11
// baseline (822.362 us; speedup 1.0000x reference)
//
#include <hip/hip_runtime.h>
#include <hip/hip_bf16.h>

// DomainSpecificHeads: out[b] = (hs[b] @ W_base + b_base) @ W_heads[idx[b]] + b_heads[idx[b]]
// B=8 S=512 D=1024 V=32000 ND=8 (slot ND = default head for out-of-range ids)

#define BCNT 8
#define SLEN 512
#define DDIM 1024
#define VDIM 32000
#define NDOM 8

typedef __attribute__((ext_vector_type(4))) float f32x4;
typedef __attribute__((ext_vector_type(8))) short bf16x8;

static __device__ __forceinline__ unsigned short f2bf(float f) {
    union { float f; unsigned int u; } x; x.f = f;
    unsigned int u = x.u;
    return (unsigned short)((u + 0x7FFFu + ((u >> 16) & 1u)) >> 16);  // RNE
}

// packed RNE f32x2 -> bf16x2 ; compiles to v_cvt_pk_bf16_f32
static __device__ __forceinline__ unsigned int pack2(float lo, float hi) {
    float2 t; t.x = lo; t.y = hi;
    union { __hip_bfloat162 h; unsigned int u; } c;
    c.h = __float22bfloat162_rn(t);
    return c.u;
}

#define SBAR()   __builtin_amdgcn_s_barrier()
#define SCHED0() __builtin_amdgcn_sched_barrier(0)

// ---------------- G1: hidden = hs @ W_base + b_base  (fp32 in, bf16 out) ----------------
// 128x128 tile, BK=64, 256 threads, 2x2 waves (validated round-1 structure).
__global__ __launch_bounds__(256)
void gemm1_k(const float* __restrict__ Af, const float* __restrict__ Bbase,
             const float* __restrict__ bias, __hip_bfloat16* __restrict__ Cb,
             int Mrows)
{
    __shared__ __align__(16) __hip_bfloat16 lds_a[128 * 64];
    __shared__ __align__(16) unsigned int   lds_b[32 * 128];

    const int tid  = threadIdx.x;
    const int lane = tid & 63;
    const int w    = tid >> 6;

    const int nwg = gridDim.x;
    const int bid = blockIdx.x;
    const int q   = nwg >> 3;
    const int sid = (bid & 7) * q + (bid >> 3);

    const int MT = Mrows >> 7;
    const int mt = sid % MT;
    const int nt = sid / MT;
    const int m0 = mt << 7;
    const int n0 = nt << 7;

    f32x4 acc[4][4];
    #pragma unroll
    for (int m = 0; m < 4; ++m)
        #pragma unroll
        for (int n = 0; n < 4; ++n)
            acc[m][n] = (f32x4)0.0f;

    const int wr = w >> 1, wc = w & 1;
    const int lr = lane & 15, lg = lane >> 4;

    for (int kt = 0; kt < DDIM / 64; ++kt) {
        const int kbase = kt * 64;

        #pragma unroll
        for (int t = 0; t < 8; ++t) {
            const int flat = (t * 256 + tid) * 4;
            const int row = flat >> 6, col = flat & 63;
            const float4 v = *(const float4*)(Af + (size_t)(m0 + row) * DDIM + kbase + col);
            uint2 pp;
            pp.x = pack2(v.x, v.y);
            pp.y = pack2(v.z, v.w);
            *(uint2*)(lds_a + flat) = pp;
        }

        #pragma unroll
        for (int t = 0; t < 4; ++t) {
            const int id = t * 256 + tid;
            const int kk = id >> 5;
            const int n  = (id & 31) << 2;
            const float* b0 = Bbase + (size_t)(kbase + 2 * kk) * DDIM + n0 + n;
            const float4 e = *(const float4*)b0;
            const float4 o = *(const float4*)(b0 + DDIM);
            uint4 pw;
            pw.x = pack2(e.x, o.x);
            pw.y = pack2(e.y, o.y);
            pw.z = pack2(e.z, o.z);
            pw.w = pack2(e.w, o.w);
            const int ns = n ^ ((kk & 4) << 2);
            *(uint4*)&lds_b[kk * 128 + ns] = pw;
        }

        __syncthreads();

        #pragma unroll
        for (int ks = 0; ks < 2; ++ks) {
            bf16x8 af[4], bfr[4];
            #pragma unroll
            for (int m = 0; m < 4; ++m) {
                const int row = wr * 64 + m * 16 + lr;
                const int k   = ks * 32 + lg * 8;
                af[m] = *(const bf16x8*)&lds_a[row * 64 + k];
            }
            #pragma unroll
            for (int n = 0; n < 4; ++n) {
                const int col = wc * 64 + n * 16 + lr;
                const int kkb = ks * 16 + lg * 4;
                union { unsigned int u[4]; bf16x8 v; } cvt;
                #pragma unroll
                for (int j = 0; j < 4; ++j) {
                    const int kk = kkb + j;
                    const int ns = col ^ ((kk & 4) << 2);
                    cvt.u[j] = lds_b[kk * 128 + ns];
                }
                bfr[n] = cvt.v;
            }
            #pragma unroll
            for (int m = 0; m < 4; ++m)
                #pragma unroll
                for (int n = 0; n < 4; ++n)
                    acc[m][n] = __builtin_amdgcn_mfma_f32_16x16x32_bf16(af[m], bfr[n], acc[m][n], 0, 0, 0);
        }

        __syncthreads();
    }

    #pragma unroll
    for (int m = 0; m < 4; ++m) {
        #pragma unroll
        for (int n = 0; n < 4; ++n) {
            const int col = n0 + wc * 64 + n * 16 + lr;
            const float bv = bias[col];
            #pragma unroll
            for (int r = 0; r < 4; ++r) {
                const int row = m0 + wr * 64 + m * 16 + lg * 4 + r;
                Cb[(size_t)row * DDIM + col] = __hip_bfloat16_raw{f2bf(acc[m][n][r] + bv)};
            }
        }
    }
}

// ---------------- G2: out = hidden @ W_heads[idx] + b_heads[idx] ----------------
// A-direct variant: A (hidden, 8 MB, L2/L3-resident) is read as per-lane
// global dwordx4 fragments DIRECTLY into registers — no LDS round-trip, no
// global_load_lds, no manual vmcnt. LDS holds ONLY B, double-buffered
// (2 x 16 KB = 32 KB) -> 3 blocks/CU at 256 threads ((256,3)).
// One barrier + one lgkmcnt(0) drain per K-step:
//   epoch t: {af/bfr(ks0) issue; WRITEB(t+1 -> nxt); LOADB(t+2); MFMA ks0;
//             af/bfr(ks1) issue; lgkmcnt(0); SBAR; MFMA ks1}
// Race audit: all ds reads of cur + writes to nxt drain at the lgkmcnt(0)
// BEFORE the barrier, so epoch t+1's WRITEB into cur cannot corrupt epoch t's
// reads; buffers alternate with kt. br4 dependencies (LOADB->WRITEB) are
// compiler-tracked counted vmcnt (no asm).
// B layout (R5-validated conflict-free): [n][kk] u32 k-pairs, quad slot
// kk ^ ((n>>1)&7)<<2 -> 8 quads x 8 lanes on write AND read.
__global__ __launch_bounds__(256, 3)
void gemm2_k(const __hip_bfloat16* __restrict__ A, const float* __restrict__ Wh,
             const float* __restrict__ bh, float* __restrict__ out,
             const int* __restrict__ dom)
{
    __shared__ __align__(16) unsigned int ldsB[2][128 * 32];   // 2 x 16 KB

    const int tid  = threadIdx.x;
    const int lane = tid & 63;
    const int w    = tid >> 6;      // 0..3
    const int wr   = w >> 1;        // 0..1
    const int wc   = w & 1;         // 0..1
    const int lr   = lane & 15;
    const int lg   = lane >> 4;

    // XCD-chunked swizzle; grid = 8000 (%8==0). XCD x streams example x's head;
    // mt innermost -> 4 M-blocks share each W panel via that XCD's L2.
    const int bid  = blockIdx.x;
    const int q    = gridDim.x >> 3;             // 1000
    const int sid  = (bid & 7) * q + (bid >> 3);
    const int mt   = sid & 3;
    const int rest = sid >> 2;
    const int nt   = rest % 250;
    const int ex   = rest / 250;
    const int m0   = ex * SLEN + mt * 128;
    const int n0   = nt * 128;

    const int di  = dom[ex];
    const int hid = (di >= 0 && di < NDOM) ? di : NDOM;
    const float* Bp   = Wh + (size_t)hid * DDIM * (size_t)VDIM;
    const float* bias = bh + (size_t)hid * (size_t)VDIM;

    f32x4 acc[4][4];
    #pragma unroll
    for (int m = 0; m < 4; ++m)
        #pragma unroll
        for (int n = 0; n < 4; ++n)
            acc[m][n] = (f32x4)0.0f;

    // A fragment base: row = m0 + wr*64 + m*16 + lr ; k = kt*64 + ks*32 + lg*8
    const __hip_bfloat16* aRow = A + (size_t)(m0 + wr * 64 + lr) * DDIM + lg * 8;

    // B staging (R5-validated 256-thread assignment): thread owns 8 k-rows x 4 cols.
    const int nb4 = (tid & 31) << 2;     // col base 0..124
    const int kb  = (tid >> 5) << 3;     // k base 0..56
    const int qb  = kb >> 1;             // kk-quad slot base (multiple of 4)

    f32x4 br4[8];

    #define LOADB(KT) do {                                                         \
        const float* _p = Bp + (size_t)((KT) * 64 + kb) * VDIM + n0 + nb4;         \
        _Pragma("unroll")                                                          \
        for (int j = 0; j < 8; ++j) br4[j] = *(const f32x4*)(_p + (size_t)j * VDIM); \
    } while (0)

    #define WRITEB(LB) do {                                                        \
        _Pragma("unroll")                                                          \
        for (int i = 0; i < 4; ++i) {                                              \
            const int col  = nb4 + i;                                              \
            const int slot = qb ^ (((col >> 1) & 7) << 2);                         \
            uint4 wv;                                                              \
            wv.x = pack2(br4[0][i], br4[1][i]);                                    \
            wv.y = pack2(br4[2][i], br4[3][i]);                                    \
            wv.z = pack2(br4[4][i], br4[5][i]);                                    \
            wv.w = pack2(br4[6][i], br4[7][i]);                                    \
            *(uint4*)&(LB)[col * 32 + slot] = wv;                                  \
        }                                                                          \
    } while (0)

    #define READ_AF(AF, KT, KS) do {                                               \
        _Pragma("unroll")                                                          \
        for (int m = 0; m < 4; ++m)                                                \
            AF[m] = *(const bf16x8*)(aRow + (size_t)(m * 16) * DDIM + (KT) * 64 + (KS) * 32); \
    } while (0)

    #define READ_BF(BF, LB, KS) do {                                               \
        _Pragma("unroll")                                                          \
        for (int n = 0; n < 4; ++n) {                                              \
            const int col  = wc * 64 + n * 16 + lr;                                \
            const int kkb  = (KS) * 16 + lg * 4;                                   \
            const int slot = kkb ^ (((col >> 1) & 7) << 2);                        \
            BF[n] = *(const bf16x8*)&(LB)[col * 32 + slot];                        \
        }                                                                          \
    } while (0)

    #define MFMA16(AF, BF) do {                                                    \
        _Pragma("unroll")                                                          \
        for (int m = 0; m < 4; ++m)                                                \
            _Pragma("unroll")                                                      \
            for (int n = 0; n < 4; ++n)                                            \
                acc[m][n] = __builtin_amdgcn_mfma_f32_16x16x32_bf16(AF[m], BF[n], acc[m][n], 0, 0, 0); \
    } while (0)

    // ---- prologue: B(0) into buf0, B(1) loads left in flight ----
    LOADB(0);
    SCHED0();
    WRITEB(ldsB[0]);          // compiler counted-vmcnt drains LOADB(0)'s 8
    SCHED0();
    LOADB(1);
    SCHED0();
    asm volatile("s_waitcnt lgkmcnt(0)" ::: "memory");
    SCHED0();
    SBAR();

    // ---- main loop: one barrier + one lgkm drain per K-step ----
    for (int kt = 0; kt < 16; ++kt) {
        unsigned int* cur = ldsB[kt & 1];
        unsigned int* nxt = ldsB[(kt + 1) & 1];

        bf16x8 af[4], bfr[4];

        // ks = 0 : frags + next-tile staging + MFMA (pre-barrier; cur written last epoch)
        READ_AF(af, kt, 0);
        READ_BF(bfr, cur, 0);
        if (kt < 15) WRITEB(nxt);       // consumes br4 = B(kt+1); waits its loads
        if (kt < 14) LOADB(kt + 2);     // 8 loads fly across this + next epoch
        SCHED0();
        __builtin_amdgcn_s_setprio(1);
        MFMA16(af, bfr);
        __builtin_amdgcn_s_setprio(0);

        // ks = 1 : frags, drain LDS ops, barrier, MFMA (post-barrier, regs valid)
        READ_AF(af, kt, 1);
        READ_BF(bfr, cur, 1);
        SCHED0();
        asm volatile("s_waitcnt lgkmcnt(0)" ::: "memory");  // all cur-reads + nxt-writes done
        SCHED0();
        if (kt < 15) SBAR();
        __builtin_amdgcn_s_setprio(1);
        MFMA16(af, bfr);
        __builtin_amdgcn_s_setprio(0);
    }

    // ---- epilogue ----
    #pragma unroll
    for (int n = 0; n < 4; ++n) {
        const int col = n0 + wc * 64 + n * 16 + lr;
        const float bv = bias[col];
        #pragma unroll
        for (int m = 0; m < 4; ++m) {
            #pragma unroll
            for (int r = 0; r < 4; ++r) {
                const int row = m0 + wr * 64 + m * 16 + lg * 4 + r;
                out[(size_t)row * VDIM + col] = acc[m][n][r] + bv;
            }
        }
    }

    #undef LOADB
    #undef WRITEB
    #undef READ_AF
    #undef READ_BF
    #undef MFMA16
}

extern "C" void kernel_launch(void* const* d_in, const int* in_sizes, int n_in,
                              void* d_out, int out_size, void* d_ws, size_t ws_size,
                              hipStream_t stream)
{
    const float* hs  = (const float*)d_in[0];   // [8,512,1024] fp32
    const int*   dom = (const int*)d_in[1];     // [8] int32
    const float* Wb  = (const float*)d_in[2];   // [1024,1024] fp32
    const float* bb  = (const float*)d_in[3];   // [1024] fp32
    const float* Wh  = (const float*)d_in[4];   // [9,1024,32000] fp32
    const float* bh  = (const float*)d_in[5];   // [9,32000] fp32
    float* out = (float*)d_out;                 // [8,512,32000] fp32
    __hip_bfloat16* hidden = (__hip_bfloat16*)d_ws;   // [4096,1024] bf16, 8 MB

    const int M = BCNT * SLEN;  // 4096

    // G1: 256 blocks of 256 threads
    const int g1 = (M / 128) * (DDIM / 128);
    hipLaunchKernelGGL(gemm1_k, dim3(g1), dim3(256), 0, stream, hs, Wb, bb, hidden, M);

    // G2: 8 ex * 4 mt * 250 nt = 8000 blocks of 256 threads
    const int g2 = BCNT * (SLEN / 128) * (VDIM / 128);
    hipLaunchKernelGGL(gemm2_k, dim3(g2), dim3(256), 0, stream, hidden, Wh, bh, out, dom);
}

// Round 12
// 756.963 us; speedup vs baseline: 1.0864x; 1.0864x over previous
//
#include <hip/hip_runtime.h>
#include <hip/hip_bf16.h>

// DomainSpecificHeads: out[b] = (hs[b] @ W_base + b_base) @ W_heads[idx[b]] + b_heads[idx[b]]
// B=8 S=512 D=1024 V=32000 ND=8 (slot ND = default head for out-of-range ids)

#define BCNT 8
#define SLEN 512
#define DDIM 1024
#define VDIM 32000
#define NDOM 8

typedef __attribute__((ext_vector_type(4))) float f32x4;
typedef __attribute__((ext_vector_type(8))) short bf16x8;

static __device__ __forceinline__ unsigned short f2bf(float f) {
    union { float f; unsigned int u; } x; x.f = f;
    unsigned int u = x.u;
    return (unsigned short)((u + 0x7FFFu + ((u >> 16) & 1u)) >> 16);  // RNE
}

// packed RNE f32x2 -> bf16x2 ; compiles to v_cvt_pk_bf16_f32
static __device__ __forceinline__ unsigned int pack2(float lo, float hi) {
    float2 t; t.x = lo; t.y = hi;
    union { __hip_bfloat162 h; unsigned int u; } c;
    c.h = __float22bfloat162_rn(t);
    return c.u;
}

#define SBAR()   __builtin_amdgcn_s_barrier()
#define SCHED0() __builtin_amdgcn_sched_barrier(0)

// ---------------- G1: hidden = hs @ W_base + b_base  (fp32 in, bf16 out) ----------------
// 128x128 tile, BK=64, 256 threads, 2x2 waves (validated round-1 structure).
__global__ __launch_bounds__(256)
void gemm1_k(const float* __restrict__ Af, const float* __restrict__ Bbase,
             const float* __restrict__ bias, __hip_bfloat16* __restrict__ Cb,
             int Mrows)
{
    __shared__ __align__(16) __hip_bfloat16 lds_a[128 * 64];
    __shared__ __align__(16) unsigned int   lds_b[32 * 128];

    const int tid  = threadIdx.x;
    const int lane = tid & 63;
    const int w    = tid >> 6;

    const int nwg = gridDim.x;
    const int bid = blockIdx.x;
    const int q   = nwg >> 3;
    const int sid = (bid & 7) * q + (bid >> 3);

    const int MT = Mrows >> 7;
    const int mt = sid % MT;
    const int nt = sid / MT;
    const int m0 = mt << 7;
    const int n0 = nt << 7;

    f32x4 acc[4][4];
    #pragma unroll
    for (int m = 0; m < 4; ++m)
        #pragma unroll
        for (int n = 0; n < 4; ++n)
            acc[m][n] = (f32x4)0.0f;

    const int wr = w >> 1, wc = w & 1;
    const int lr = lane & 15, lg = lane >> 4;

    for (int kt = 0; kt < DDIM / 64; ++kt) {
        const int kbase = kt * 64;

        #pragma unroll
        for (int t = 0; t < 8; ++t) {
            const int flat = (t * 256 + tid) * 4;
            const int row = flat >> 6, col = flat & 63;
            const float4 v = *(const float4*)(Af + (size_t)(m0 + row) * DDIM + kbase + col);
            uint2 pp;
            pp.x = pack2(v.x, v.y);
            pp.y = pack2(v.z, v.w);
            *(uint2*)(lds_a + flat) = pp;
        }

        #pragma unroll
        for (int t = 0; t < 4; ++t) {
            const int id = t * 256 + tid;
            const int kk = id >> 5;
            const int n  = (id & 31) << 2;
            const float* b0 = Bbase + (size_t)(kbase + 2 * kk) * DDIM + n0 + n;
            const float4 e = *(const float4*)b0;
            const float4 o = *(const float4*)(b0 + DDIM);
            uint4 pw;
            pw.x = pack2(e.x, o.x);
            pw.y = pack2(e.y, o.y);
            pw.z = pack2(e.z, o.z);
            pw.w = pack2(e.w, o.w);
            const int ns = n ^ ((kk & 4) << 2);
            *(uint4*)&lds_b[kk * 128 + ns] = pw;
        }

        __syncthreads();

        #pragma unroll
        for (int ks = 0; ks < 2; ++ks) {
            bf16x8 af[4], bfr[4];
            #pragma unroll
            for (int m = 0; m < 4; ++m) {
                const int row = wr * 64 + m * 16 + lr;
                const int k   = ks * 32 + lg * 8;
                af[m] = *(const bf16x8*)&lds_a[row * 64 + k];
            }
            #pragma unroll
            for (int n = 0; n < 4; ++n) {
                const int col = wc * 64 + n * 16 + lr;
                const int kkb = ks * 16 + lg * 4;
                union { unsigned int u[4]; bf16x8 v; } cvt;
                #pragma unroll
                for (int j = 0; j < 4; ++j) {
                    const int kk = kkb + j;
                    const int ns = col ^ ((kk & 4) << 2);
                    cvt.u[j] = lds_b[kk * 128 + ns];
                }
                bfr[n] = cvt.v;
            }
            #pragma unroll
            for (int m = 0; m < 4; ++m)
                #pragma unroll
                for (int n = 0; n < 4; ++n)
                    acc[m][n] = __builtin_amdgcn_mfma_f32_16x16x32_bf16(af[m], bfr[n], acc[m][n], 0, 0, 0);
        }

        __syncthreads();
    }

    #pragma unroll
    for (int m = 0; m < 4; ++m) {
        #pragma unroll
        for (int n = 0; n < 4; ++n) {
            const int col = n0 + wc * 64 + n * 16 + lr;
            const float bv = bias[col];
            #pragma unroll
            for (int r = 0; r < 4; ++r) {
                const int row = m0 + wr * 64 + m * 16 + lg * 4 + r;
                Cb[(size_t)row * DDIM + col] = __hip_bfloat16_raw{f2bf(acc[m][n][r] + bv)};
            }
        }
    }
}

// ---------------- G2: out = hidden @ W_heads[idx] + b_heads[idx] ----------------
// A-direct + FULL-EPOCH register prefetch (R11 fix, T14 issue-early/use-late):
//   A-fragments for K-tile t+1 are loaded into regs at the START of epoch t
//   (rA0/rA1 ping-pong, 2-epoch unrolled loop -> all static indexing, rule 20).
//   The whole epoch (~2000 cyc) covers the ~200-300 cyc L2 latency that R11
//   exposed (R11: issue->use gap ~20 instrs, G2 850 us, MfmaUtil 13.5%).
// B: fp32 reg-staged -> bf16 k-pair u32, conflict-free [n][kk] quad-XOR layout
//   (R5-validated), DOUBLE-buffered LDS (2 x 16 KB) -> stage-first, ONE
//   barrier + one vmcnt(8)+lgkmcnt(0) per K-step (catalog minimum-2-phase).
// FIFO vmcnt audit (per epoch, SCHED0-pinned): enter with br4's 8 B-loads
//   outstanding -> +8 A-loads (LOADA t+1) -> WRITEB drains br4 (compiler
//   vmcnt(8), leaves A) -> +8 B-loads (LOADB t+2) -> compute (no vmem) ->
//   explicit vmcnt(8) drains exactly the A-loads, keeps B in flight. (T4:
//   never drain to 0 mid-loop.)
// LDS traffic: 48 KB/K-step (B only) vs 176 KB for the staged-A variants.
__global__ __launch_bounds__(256, 2)
void gemm2_k(const __hip_bfloat16* __restrict__ A, const float* __restrict__ Wh,
             const float* __restrict__ bh, float* __restrict__ out,
             const int* __restrict__ dom)
{
    __shared__ __align__(16) unsigned int ldsB[2][128 * 32];   // 2 x 16 KB

    const int tid  = threadIdx.x;
    const int lane = tid & 63;
    const int w    = tid >> 6;      // 0..3
    const int wr   = w >> 1;        // 0..1
    const int wc   = w & 1;         // 0..1
    const int lr   = lane & 15;
    const int lg   = lane >> 4;

    // XCD-chunked swizzle; grid = 8000 (%8==0). XCD x streams example x's head;
    // mt innermost -> 4 M-blocks share each W panel via that XCD's L2.
    const int bid  = blockIdx.x;
    const int q    = gridDim.x >> 3;             // 1000
    const int sid  = (bid & 7) * q + (bid >> 3);
    const int mt   = sid & 3;
    const int rest = sid >> 2;
    const int nt   = rest % 250;
    const int ex   = rest / 250;
    const int m0   = ex * SLEN + mt * 128;
    const int n0   = nt * 128;

    const int di  = dom[ex];
    const int hid = (di >= 0 && di < NDOM) ? di : NDOM;
    const float* Bp   = Wh + (size_t)hid * DDIM * (size_t)VDIM;
    const float* bias = bh + (size_t)hid * (size_t)VDIM;

    f32x4 acc[4][4];
    #pragma unroll
    for (int m = 0; m < 4; ++m)
        #pragma unroll
        for (int n = 0; n < 4; ++n)
            acc[m][n] = (f32x4)0.0f;

    // A fragment base: row = m0 + wr*64 + m*16 + lr ; k = kt*64 + ks*32 + lg*8
    const __hip_bfloat16* aRow = A + (size_t)(m0 + wr * 64 + lr) * DDIM + lg * 8;

    // B staging (R5-validated 256-thread assignment): thread owns 8 k-rows x 4 cols.
    const int nb4 = (tid & 31) << 2;     // col base 0..124
    const int kb  = (tid >> 5) << 3;     // k base 0..56
    const int qb  = kb >> 1;             // kk-quad slot base (multiple of 4)

    f32x4  br4[8];
    bf16x8 rA0[8], rA1[8];               // A frags for one K-tile: [ks*4+m]

    #define LOADB(KT) do {                                                         \
        const float* _p = Bp + (size_t)((KT) * 64 + kb) * VDIM + n0 + nb4;         \
        _Pragma("unroll")                                                          \
        for (int j = 0; j < 8; ++j) br4[j] = *(const f32x4*)(_p + (size_t)j * VDIM); \
    } while (0)

    #define WRITEB(LB) do {                                                        \
        _Pragma("unroll")                                                          \
        for (int i = 0; i < 4; ++i) {                                              \
            const int col  = nb4 + i;                                              \
            const int slot = qb ^ (((col >> 1) & 7) << 2);                         \
            uint4 wv;                                                              \
            wv.x = pack2(br4[0][i], br4[1][i]);                                    \
            wv.y = pack2(br4[2][i], br4[3][i]);                                    \
            wv.z = pack2(br4[4][i], br4[5][i]);                                    \
            wv.w = pack2(br4[6][i], br4[7][i]);                                    \
            *(uint4*)&(LB)[col * 32 + slot] = wv;                                  \
        }                                                                          \
    } while (0)

    #define LOADA(AR, KT) do {                                                     \
        _Pragma("unroll")                                                          \
        for (int ks = 0; ks < 2; ++ks)                                             \
            _Pragma("unroll")                                                      \
            for (int m = 0; m < 4; ++m)                                            \
                AR[ks * 4 + m] = *(const bf16x8*)(aRow + (size_t)(m * 16) * DDIM + (KT) * 64 + ks * 32); \
    } while (0)

    #define READ_BF(BF, LB, KS) do {                                               \
        _Pragma("unroll")                                                          \
        for (int n = 0; n < 4; ++n) {                                              \
            const int col  = wc * 64 + n * 16 + lr;                                \
            const int kkb  = (KS) * 16 + lg * 4;                                   \
            const int slot = kkb ^ (((col >> 1) & 7) << 2);                        \
            BF[n] = *(const bf16x8*)&(LB)[col * 32 + slot];                        \
        }                                                                          \
    } while (0)

    // compute one K-tile from register A-frags (AR) + LDS B buffer (LB)
    #define COMPUTE_E(AR, LB) do {                                                 \
        bf16x8 bfr[4];                                                             \
        READ_BF(bfr, LB, 0);                                                       \
        __builtin_amdgcn_s_setprio(1);                                             \
        _Pragma("unroll")                                                          \
        for (int m = 0; m < 4; ++m)                                                \
            _Pragma("unroll")                                                      \
            for (int n = 0; n < 4; ++n)                                            \
                acc[m][n] = __builtin_amdgcn_mfma_f32_16x16x32_bf16(AR[m], bfr[n], acc[m][n], 0, 0, 0); \
        __builtin_amdgcn_s_setprio(0);                                             \
        READ_BF(bfr, LB, 1);                                                       \
        __builtin_amdgcn_s_setprio(1);                                             \
        _Pragma("unroll")                                                          \
        for (int m = 0; m < 4; ++m)                                                \
            _Pragma("unroll")                                                      \
            for (int n = 0; n < 4; ++n)                                            \
                acc[m][n] = __builtin_amdgcn_mfma_f32_16x16x32_bf16(AR[4 + m], bfr[n], acc[m][n], 0, 0, 0); \
        __builtin_amdgcn_s_setprio(0);                                             \
    } while (0)

    // ---- prologue: B(0)->buf0, A(0)->rA0, br4=B(1) left in flight ----
    LOADB(0);
    SCHED0();
    LOADA(rA0, 0);
    SCHED0();
    WRITEB(ldsB[0]);          // compiler vmcnt(8): drains LOADB(0), leaves rA0 loads
    SCHED0();
    LOADB(1);
    SCHED0();
    asm volatile("s_waitcnt vmcnt(8) lgkmcnt(0)" ::: "memory");  // drains rA0; keeps B(1)
    SCHED0();
    SBAR();

    // ---- main loop: 2-epoch unrolled (static rA0/rA1 + buf0/buf1 ping-pong) ----
    for (int t = 0; t < 14; t += 2) {
        // epoch t (even): consume rA0 + buf0; prefetch A(t+1)->rA1, B(t+1)->buf1, B(t+2)->br4
        LOADA(rA1, t + 1);
        SCHED0();
        WRITEB(ldsB[1]);      // br4 = B(t+1); compiler vmcnt(8) leaves the A-loads
        SCHED0();
        LOADB(t + 2);
        SCHED0();
        COMPUTE_E(rA0, ldsB[0]);
        SCHED0();
        asm volatile("s_waitcnt vmcnt(8) lgkmcnt(0)" ::: "memory");  // drain A(t+1); keep B(t+2)
        SCHED0();
        SBAR();

        // epoch t+1 (odd): consume rA1 + buf1; prefetch A(t+2)->rA0, B(t+2)->buf0, B(t+3)->br4
        LOADA(rA0, t + 2);
        SCHED0();
        WRITEB(ldsB[0]);      // br4 = B(t+2)
        SCHED0();
        LOADB(t + 3);
        SCHED0();
        COMPUTE_E(rA1, ldsB[1]);
        SCHED0();
        asm volatile("s_waitcnt vmcnt(8) lgkmcnt(0)" ::: "memory");
        SCHED0();
        SBAR();
    }

    // epoch 14: consume rA0 + buf0; prefetch A(15)->rA1, B(15)->buf1; no LOADB
    LOADA(rA1, 15);
    SCHED0();
    WRITEB(ldsB[1]);          // br4 = B(15), loaded at epoch 13
    SCHED0();
    COMPUTE_E(rA0, ldsB[0]);
    SCHED0();
    asm volatile("s_waitcnt vmcnt(0) lgkmcnt(0)" ::: "memory");   // only A(15) in flight
    SCHED0();
    SBAR();

    // epoch 15: compute only
    COMPUTE_E(rA1, ldsB[1]);

    // ---- epilogue ----
    #pragma unroll
    for (int n = 0; n < 4; ++n) {
        const int col = n0 + wc * 64 + n * 16 + lr;
        const float bv = bias[col];
        #pragma unroll
        for (int m = 0; m < 4; ++m) {
            #pragma unroll
            for (int r = 0; r < 4; ++r) {
                const int row = m0 + wr * 64 + m * 16 + lg * 4 + r;
                out[(size_t)row * VDIM + col] = acc[m][n][r] + bv;
            }
        }
    }

    #undef LOADB
    #undef WRITEB
    #undef LOADA
    #undef READ_BF
    #undef COMPUTE_E
}

extern "C" void kernel_launch(void* const* d_in, const int* in_sizes, int n_in,
                              void* d_out, int out_size, void* d_ws, size_t ws_size,
                              hipStream_t stream)
{
    const float* hs  = (const float*)d_in[0];   // [8,512,1024] fp32
    const int*   dom = (const int*)d_in[1];     // [8] int32
    const float* Wb  = (const float*)d_in[2];   // [1024,1024] fp32
    const float* bb  = (const float*)d_in[3];   // [1024] fp32
    const float* Wh  = (const float*)d_in[4];   // [9,1024,32000] fp32
    const float* bh  = (const float*)d_in[5];   // [9,32000] fp32
    float* out = (float*)d_out;                 // [8,512,32000] fp32
    __hip_bfloat16* hidden = (__hip_bfloat16*)d_ws;   // [4096,1024] bf16, 8 MB

    const int M = BCNT * SLEN;  // 4096

    // G1: 256 blocks of 256 threads
    const int g1 = (M / 128) * (DDIM / 128);
    hipLaunchKernelGGL(gemm1_k, dim3(g1), dim3(256), 0, stream, hs, Wb, bb, hidden, M);

    // G2: 8 ex * 4 mt * 250 nt = 8000 blocks of 256 threads
    const int g2 = BCNT * (SLEN / 128) * (VDIM / 128);
    hipLaunchKernelGGL(gemm2_k, dim3(g2), dim3(256), 0, stream, hidden, Wh, bh, out, dom);
}

// Round 13
// 547.805 us; speedup vs baseline: 1.5012x; 1.3818x over previous
//
#include <hip/hip_runtime.h>
#include <hip/hip_bf16.h>

// DomainSpecificHeads: out[b] = (hs[b] @ W_base + b_base) @ W_heads[idx[b]] + b_heads[idx[b]]
// B=8 S=512 D=1024 V=32000 ND=8 (slot ND = default head for out-of-range ids)

#define BCNT 8
#define SLEN 512
#define DDIM 1024
#define VDIM 32000
#define NDOM 8

typedef __attribute__((ext_vector_type(4))) float f32x4;
typedef __attribute__((ext_vector_type(8))) short bf16x8;

static __device__ __forceinline__ unsigned short f2bf(float f) {
    union { float f; unsigned int u; } x; x.f = f;
    unsigned int u = x.u;
    return (unsigned short)((u + 0x7FFFu + ((u >> 16) & 1u)) >> 16);  // RNE
}

// packed RNE f32x2 -> bf16x2 ; compiles to v_cvt_pk_bf16_f32 (m240: let compiler fuse)
static __device__ __forceinline__ unsigned int pack2(float lo, float hi) {
    float2 t; t.x = lo; t.y = hi;
    union { __hip_bfloat162 h; unsigned int u; } c;
    c.h = __float22bfloat162_rn(t);
    return c.u;
}

#define SBAR()   __builtin_amdgcn_s_barrier()
#define SCHED0() __builtin_amdgcn_sched_barrier(0)

// ---------------- G1: hidden = hs @ W_base + b_base  (fp32 in, bf16 out) ----------------
// 128x128 tile, BK=64, 256 threads, 2x2 waves (validated round-1 structure).
__global__ __launch_bounds__(256)
void gemm1_k(const float* __restrict__ Af, const float* __restrict__ Bbase,
             const float* __restrict__ bias, __hip_bfloat16* __restrict__ Cb,
             int Mrows)
{
    __shared__ __align__(16) __hip_bfloat16 lds_a[128 * 64];
    __shared__ __align__(16) unsigned int   lds_b[32 * 128];

    const int tid  = threadIdx.x;
    const int lane = tid & 63;
    const int w    = tid >> 6;

    const int nwg = gridDim.x;
    const int bid = blockIdx.x;
    const int q   = nwg >> 3;
    const int sid = (bid & 7) * q + (bid >> 3);

    const int MT = Mrows >> 7;
    const int mt = sid % MT;
    const int nt = sid / MT;
    const int m0 = mt << 7;
    const int n0 = nt << 7;

    f32x4 acc[4][4];
    #pragma unroll
    for (int m = 0; m < 4; ++m)
        #pragma unroll
        for (int n = 0; n < 4; ++n)
            acc[m][n] = (f32x4)0.0f;

    const int wr = w >> 1, wc = w & 1;
    const int lr = lane & 15, lg = lane >> 4;

    for (int kt = 0; kt < DDIM / 64; ++kt) {
        const int kbase = kt * 64;

        #pragma unroll
        for (int t = 0; t < 8; ++t) {
            const int flat = (t * 256 + tid) * 4;
            const int row = flat >> 6, col = flat & 63;
            const float4 v = *(const float4*)(Af + (size_t)(m0 + row) * DDIM + kbase + col);
            uint2 pp;
            pp.x = pack2(v.x, v.y);
            pp.y = pack2(v.z, v.w);
            *(uint2*)(lds_a + flat) = pp;
        }

        #pragma unroll
        for (int t = 0; t < 4; ++t) {
            const int id = t * 256 + tid;
            const int kk = id >> 5;
            const int n  = (id & 31) << 2;
            const float* b0 = Bbase + (size_t)(kbase + 2 * kk) * DDIM + n0 + n;
            const float4 e = *(const float4*)b0;
            const float4 o = *(const float4*)(b0 + DDIM);
            uint4 pw;
            pw.x = pack2(e.x, o.x);
            pw.y = pack2(e.y, o.y);
            pw.z = pack2(e.z, o.z);
            pw.w = pack2(e.w, o.w);
            const int ns = n ^ ((kk & 4) << 2);
            *(uint4*)&lds_b[kk * 128 + ns] = pw;
        }

        __syncthreads();

        #pragma unroll
        for (int ks = 0; ks < 2; ++ks) {
            bf16x8 af[4], bfr[4];
            #pragma unroll
            for (int m = 0; m < 4; ++m) {
                const int row = wr * 64 + m * 16 + lr;
                const int k   = ks * 32 + lg * 8;
                af[m] = *(const bf16x8*)&lds_a[row * 64 + k];
            }
            #pragma unroll
            for (int n = 0; n < 4; ++n) {
                const int col = wc * 64 + n * 16 + lr;
                const int kkb = ks * 16 + lg * 4;
                union { unsigned int u[4]; bf16x8 v; } cvt;
                #pragma unroll
                for (int j = 0; j < 4; ++j) {
                    const int kk = kkb + j;
                    const int ns = col ^ ((kk & 4) << 2);
                    cvt.u[j] = lds_b[kk * 128 + ns];
                }
                bfr[n] = cvt.v;
            }
            #pragma unroll
            for (int m = 0; m < 4; ++m)
                #pragma unroll
                for (int n = 0; n < 4; ++n)
                    acc[m][n] = __builtin_amdgcn_mfma_f32_16x16x32_bf16(af[m], bfr[n], acc[m][n], 0, 0, 0);
        }

        __syncthreads();
    }

    #pragma unroll
    for (int m = 0; m < 4; ++m) {
        #pragma unroll
        for (int n = 0; n < 4; ++n) {
            const int col = n0 + wc * 64 + n * 16 + lr;
            const float bv = bias[col];
            #pragma unroll
            for (int r = 0; r < 4; ++r) {
                const int row = m0 + wr * 64 + m * 16 + lg * 4 + r;
                Cb[(size_t)row * DDIM + col] = __hip_bfloat16_raw{f2bf(acc[m][n][r] + bv)};
            }
        }
    }
}

// ---------------- G2: out = hidden @ W_heads[idx] + b_heads[idx] ----------------
// R7 kernel VERBATIM except the block-index map (R13 change):
// EXAMPLE-SERIALIZED dispatch — blocks 0..499 are example 0, 500..999 example 1,
// etc. The whole chip processes ~one example (one head, 131 MB fp32) at a time,
// so the concurrent W working set fits the 256 MB L3 and the 2x mt-panel
// re-reads hit L3/L2 instead of thrashing (R12 diagnosis: all-8-examples
// concurrent = 626 MB >> L3 -> every W load HBM-latency class, MfmaUtil
// pinned at ~15% across six schedule variants). No XCD swizzle: panel
// sharing now flows through the chip-level L3, which all XCDs see.
// Everything else (BM=256 BN=128 BK=64, 512 threads, 48 KB single-buffer LDS,
// 2-barrier K-step, SCHED0-pinned clusters, counted vmcnt(8)) is the
// race-validated R5/R7 skeleton, unchanged.
__global__ __launch_bounds__(512, 4)
void gemm2_k(const __hip_bfloat16* __restrict__ A, const float* __restrict__ Wh,
             const float* __restrict__ bh, float* __restrict__ out,
             const int* __restrict__ dom)
{
    __shared__ __align__(16) __hip_bfloat16 ldsA[256 * 64];   // 32 KB
    __shared__ __align__(16) unsigned int   ldsB[128 * 32];   // 16 KB, [n][kk] u32 k-pairs

    const int tid  = threadIdx.x;
    const int lane = tid & 63;
    const int w    = tid >> 6;      // 0..7
    const int wr   = w >> 1;        // 0..3 -> 64-row stripe
    const int wc   = w & 1;         // 0..1 -> 64-col stripe
    const int lr   = lane & 15;
    const int lg   = lane >> 4;

    // ---- R13: example-major dispatch order (see header comment) ----
    const int bid = blockIdx.x;     // grid = 4000 = 8 ex * 500
    const int ex  = bid / 500;      // example-major: chip finishes ex e before e+1
    const int r   = bid % 500;
    const int mt  = r & 1;          // mt-pair adjacent in dispatch -> co-resident
    const int nt  = r >> 1;         // 0..249
    const int m0  = ex * SLEN + mt * 256;
    const int n0  = nt * 128;

    const int di  = dom[ex];
    const int hid = (di >= 0 && di < NDOM) ? di : NDOM;
    const float* Bp   = Wh + (size_t)hid * DDIM * (size_t)VDIM;
    const float* bias = bh + (size_t)hid * (size_t)VDIM;

    f32x4 acc[4][4];
    #pragma unroll
    for (int m = 0; m < 4; ++m)
        #pragma unroll
        for (int n = 0; n < 4; ++n)
            acc[m][n] = (f32x4)0.0f;

    // B staging: thread owns 8 k-rows x 2 cols (float2); 512 threads cover 64x128.
    const int nb  = (tid & 63) << 1;     // col base 0..126 (even)
    const int kb  = (tid >> 6) << 3;     // k base 0..56 (8 rows per wave)
    const int qb  = kb >> 1;             // kk-quad slot base (multiple of 4)
    const int bsw = (lane & 7) << 2;     // == ((nb>>1)&7)<<2
    const int bslot = qb ^ bsw;

    float2 br[8];

    #define LOADB(KT) do {                                                         \
        const float* _p = Bp + (size_t)((KT) * 64 + kb) * VDIM + n0 + nb;          \
        _Pragma("unroll")                                                          \
        for (int j = 0; j < 8; ++j) br[j] = *(const float2*)(_p + (size_t)j * VDIM); \
    } while (0)

    #define WRITEB() do {                                                          \
        uint4 w0, w1;                                                              \
        w0.x = pack2(br[0].x, br[1].x); w0.y = pack2(br[2].x, br[3].x);            \
        w0.z = pack2(br[4].x, br[5].x); w0.w = pack2(br[6].x, br[7].x);            \
        w1.x = pack2(br[0].y, br[1].y); w1.y = pack2(br[2].y, br[3].y);            \
        w1.z = pack2(br[4].y, br[5].y); w1.w = pack2(br[6].y, br[7].y);            \
        *(uint4*)&ldsB[nb * 32 + bslot]       = w0;                                \
        *(uint4*)&ldsB[(nb + 1) * 32 + bslot] = w1;                                \
    } while (0)

    #define STAGEA(KT) do {                                                        \
        _Pragma("unroll")                                                          \
        for (int i = 0; i < 4; ++i) {                                              \
            const int base_e = (i * 8 + w) * 512;                                  \
            const int flat   = base_e + lane * 8;                                  \
            const int row    = flat >> 6;                                          \
            const int kbyte  = (flat & 63) * 2;                                    \
            const int srck   = (kbyte ^ ((row & 7) << 4)) >> 1;                    \
            const __hip_bfloat16* src = A + (size_t)(m0 + row) * DDIM + (KT) * 64 + srck; \
            __builtin_amdgcn_global_load_lds(                                      \
                (const __attribute__((address_space(1))) unsigned int*)src,        \
                (__attribute__((address_space(3))) unsigned int*)(ldsA + base_e),  \
                16, 0, 0);                                                         \
        }                                                                          \
    } while (0)

    #define COMPUTE() do {                                                         \
        _Pragma("unroll")                                                          \
        for (int ks = 0; ks < 2; ++ks) {                                           \
            bf16x8 af[4], bfr[4];                                                  \
            _Pragma("unroll")                                                      \
            for (int m = 0; m < 4; ++m) {                                          \
                const int row = wr * 64 + m * 16 + lr;                             \
                const int kby = ks * 64 + lg * 16;                                 \
                const int eff = kby ^ ((row & 7) << 4);                            \
                af[m] = *(const bf16x8*)&ldsA[row * 64 + (eff >> 1)];              \
            }                                                                      \
            _Pragma("unroll")                                                      \
            for (int n = 0; n < 4; ++n) {                                          \
                const int col  = wc * 64 + n * 16 + lr;                            \
                const int kkb  = ks * 16 + lg * 4;                                 \
                const int slot = kkb ^ (((col >> 1) & 7) << 2);                    \
                bfr[n] = *(const bf16x8*)&ldsB[col * 32 + slot];                   \
            }                                                                      \
            _Pragma("unroll")                                                      \
            for (int m = 0; m < 4; ++m)                                            \
                _Pragma("unroll")                                                  \
                for (int n = 0; n < 4; ++n)                                        \
                    acc[m][n] = __builtin_amdgcn_mfma_f32_16x16x32_bf16(af[m], bfr[n], acc[m][n], 0, 0, 0); \
        }                                                                          \
    } while (0)

    // ---- prologue (order pinned: LOADB(0) | STAGEA(0) | WRITEB | LOADB(1) | wait) ----
    LOADB(0);
    SCHED0();
    STAGEA(0);
    SCHED0();
    WRITEB();                 // compiler-inserted vmcnt drains LOADB(0)'s 8
    SCHED0();
    LOADB(1);                 // stays in flight across compute
    SCHED0();
    asm volatile("s_waitcnt vmcnt(8) lgkmcnt(0)" ::: "memory");  // drains STAGEA(0)'s 4 gll + LDS writes
    SCHED0();
    SBAR();

    // ---- main loop: compute(kt) -> barrier -> stage(kt+1) -> wait -> barrier ----
    for (int kt = 0; kt < 16; ++kt) {
        COMPUTE();
        if (kt < 15) {
            SCHED0();
            SBAR();                       // all waves done reading LDS
            SCHED0();
            STAGEA(kt + 1);               // 4x global_load_lds per wave
            SCHED0();
            WRITEB();                     // br holds B(kt+1); compiler drains its 8 loads
            SCHED0();
            if (kt < 14) {
                LOADB(kt + 2);            // 8 loads fly across next compute
                SCHED0();
                asm volatile("s_waitcnt vmcnt(8) lgkmcnt(0)" ::: "memory");
            } else {
                asm volatile("s_waitcnt vmcnt(0) lgkmcnt(0)" ::: "memory");
            }
            SCHED0();
            SBAR();
        }
    }

    // ---- epilogue ----
    #pragma unroll
    for (int n = 0; n < 4; ++n) {
        const int col = n0 + wc * 64 + n * 16 + lr;
        const float bv = bias[col];
        #pragma unroll
        for (int m = 0; m < 4; ++m) {
            #pragma unroll
            for (int r = 0; r < 4; ++r) {
                const int row = m0 + wr * 64 + m * 16 + lg * 4 + r;
                out[(size_t)row * VDIM + col] = acc[m][n][r] + bv;
            }
        }
    }

    #undef LOADB
    #undef WRITEB
    #undef STAGEA
    #undef COMPUTE
}

extern "C" void kernel_launch(void* const* d_in, const int* in_sizes, int n_in,
                              void* d_out, int out_size, void* d_ws, size_t ws_size,
                              hipStream_t stream)
{
    const float* hs  = (const float*)d_in[0];   // [8,512,1024] fp32
    const int*   dom = (const int*)d_in[1];     // [8] int32
    const float* Wb  = (const float*)d_in[2];   // [1024,1024] fp32
    const float* bb  = (const float*)d_in[3];   // [1024] fp32
    const float* Wh  = (const float*)d_in[4];   // [9,1024,32000] fp32
    const float* bh  = (const float*)d_in[5];   // [9,32000] fp32
    float* out = (float*)d_out;                 // [8,512,32000] fp32
    __hip_bfloat16* hidden = (__hip_bfloat16*)d_ws;   // [4096,1024] bf16, 8 MB

    const int M = BCNT * SLEN;  // 4096

    // G1: 256 blocks of 256 threads
    const int g1 = (M / 128) * (DDIM / 128);
    hipLaunchKernelGGL(gemm1_k, dim3(g1), dim3(256), 0, stream, hs, Wb, bb, hidden, M);

    // G2: 8 ex * 2 mt * 250 nt = 4000 blocks of 512 threads, example-major order
    const int g2 = BCNT * (SLEN / 256) * (VDIM / 128);
    hipLaunchKernelGGL(gemm2_k, dim3(g2), dim3(512), 0, stream, hidden, Wh, bh, out, dom);
}